// Round 5
// baseline (510.521 us; speedup 1.0000x reference)
//
#include <hip/hip_runtime.h>

// MessagePassingNet on MI355X — Round 5:
//   * edge kernel software-pipelined: 4 tiles/WG, register prefetch of next
//     tile's Yd/Ys gather, raw lgkmcnt-only barriers (keep loads in flight)
//   * scan kernels merged (13 -> 10 launches)
//   * layer-0 hoist, split-bf16 MFMA, counting sort as R4

constexpr int N_ATOMS = 131072;
constexpr int N_EDGES = 1048576;
constexpr int DD      = 64;
constexpr int OUTD    = 16;
constexpr int SH      = 72;   // halfword stride for 64-wide hi/lo LDS tiles
constexpr int SA      = 136;  // halfword stride for 128-wide tier-2 A tiles
constexpr int PADE    = 68;   // fp32 LDS row stride
constexpr int TILES   = 4;    // edge tiles per WG (pipeline depth)

typedef __bf16 bf16x8 __attribute__((ext_vector_type(8)));
typedef float  f32x4  __attribute__((ext_vector_type(4)));

#define DEV_INLINE __device__ __forceinline__

// Workgroup barrier that waits ONLY on LDS ops (lgkmcnt) — does NOT drain
// vmcnt, so prefetched global loads stay in flight across it. All inter-wave
// hazards in the edge tile loop are LDS-only.
DEV_INLINE void bar_lds() {
  asm volatile("s_waitcnt lgkmcnt(0)\ns_barrier" ::: "memory");
}

DEV_INLINE float relu(float x) { return x > 0.f ? x : 0.f; }

DEV_INLINE unsigned short bfbits(float x) {
  __bf16 h = (__bf16)x;
  return __builtin_bit_cast(unsigned short, h);
}
DEV_INLINE float bfval(unsigned short u) {
  unsigned int v = ((unsigned int)u) << 16;
  return __builtin_bit_cast(float, v);
}
DEV_INLINE f32x4 mfma16(bf16x8 a, bf16x8 b, f32x4 c) {
  return __builtin_amdgcn_mfma_f32_16x16x32_bf16(a, b, c, 0, 0, 0);
}
DEV_INLINE bf16x8 ldfrag(const unsigned short* p) { return *(const bf16x8*)p; }

// ===========================================================================
// Counting sort
// ===========================================================================
__global__ void hist_kernel(const int* __restrict__ edge_dst,
                            int* __restrict__ counters) {
  int i = blockIdx.x * blockDim.x + threadIdx.x;
  if (i < N_EDGES) atomicAdd(&counters[edge_dst[i]], 1);
}

__global__ void blocksum_kernel(const int* __restrict__ counters,
                                int* __restrict__ partial) {
  __shared__ int s[256];
  int t = threadIdx.x;
  s[t] = counters[blockIdx.x * 256 + t];
  __syncthreads();
  for (int off = 128; off > 0; off >>= 1) {
    if (t < off) s[t] += s[t + off];
    __syncthreads();
  }
  if (t == 0) partial[blockIdx.x] = s[0];
}

// merged: inline prefix over 512 partials + local scan -> cursor
__global__ void scanwrite_kernel(const int* __restrict__ counters,
                                 const int* __restrict__ partial,
                                 int* __restrict__ cursor) {
  __shared__ int s[256];
  __shared__ int pS[256];
  int t = threadIdx.x, b = blockIdx.x;

  int acc = 0;
  int p0 = partial[t];       if (t < b)       acc += p0;
  int p1 = partial[256 + t]; if (256 + t < b) acc += p1;
  pS[t] = acc;
  __syncthreads();
  for (int off = 128; off > 0; off >>= 1) {
    if (t < off) pS[t] += pS[t + off];
    __syncthreads();
  }
  const int base = pS[0];

  int v = counters[b * 256 + t];
  s[t] = v;
  __syncthreads();
  for (int off = 1; off < 256; off <<= 1) {
    int x = (t >= off) ? s[t - off] : 0;
    __syncthreads();
    s[t] += x;
    __syncthreads();
  }
  cursor[b * 256 + t] = base + s[t] - v;  // exclusive
}

__global__ void scatter_kernel(const int* __restrict__ edge_dst,
                               int* __restrict__ cursor,
                               int* __restrict__ eids) {
  int i = blockIdx.x * blockDim.x + threadIdx.x;
  if (i < N_EDGES) {
    int pos = atomicAdd(&cursor[edge_dst[i]], 1);
    eids[pos] = i;
  }
}

// ===========================================================================
// Weight prep: 6 sections of 64x64 in B-fragment order, hi/lo split.
//   sec 0: W0 rows 0..63 (dst)  sec 1: W0 rows 64..127 (src)
//   sec 2: W1  sec 3: W2  sec 4: FC1  sec 5: FC2
// fo(sec,j,s,l) = sec*4096 + ((j*2+s)*64 + l)*8
// ===========================================================================
__global__ void weight_prep(const float* __restrict__ w0,
                            const float* __restrict__ w1,
                            const float* __restrict__ w2,
                            const float* __restrict__ f1,
                            const float* __restrict__ f2,
                            unsigned short* __restrict__ whi,
                            unsigned short* __restrict__ wlo) {
  int tid = blockIdx.x * blockDim.x + threadIdx.x;   // 0..3071
  int sec = tid >> 9, rel = tid & 511;
  const float* w; int rowoff = 0;
  switch (sec) {
    case 0: w = w0; rowoff = 0;  break;
    case 1: w = w0; rowoff = 64; break;
    case 2: w = w1; break;
    case 3: w = w2; break;
    case 4: w = f1; break;
    default: w = f2; break;
  }
  const int tile = rel >> 6, lane = rel & 63;
  const int j = tile >> 1, s = tile & 1;
  const int n  = j * 16 + (lane & 15);
  const int kb = s * 32 + (lane >> 4) * 8;
  const int out = sec * 4096 + (tile * 64 + lane) * 8;
#pragma unroll
  for (int i = 0; i < 8; ++i) {
    float v = w[(rowoff + kb + i) * 64 + n];
    unsigned short h = bfbits(v);
    whi[out + i] = h;
    wlo[out + i] = bfbits(v - bfval(h));
  }
}

// ===========================================================================
// atom_pre: Yd = X·W0d + b0, Ys = X·W0s (split-bf16 MFMA), 64 atoms/WG.
// ===========================================================================
__global__ __launch_bounds__(256, 4)
void atom_pre(const float* __restrict__ X,
              const unsigned short* __restrict__ whi,
              const unsigned short* __restrict__ wlo,
              const float* __restrict__ b0,
              float* __restrict__ Yd, float* __restrict__ Ys)
{
  __shared__ __align__(16) unsigned short Xh[64 * SH];
  __shared__ __align__(16) unsigned short Xl[64 * SH];

  const int t  = threadIdx.x;
  const int a0 = blockIdx.x * 64;

  {
    const int r  = t >> 2;
    const int k0 = (t & 3) * 16;
    const float4* s4 = (const float4*)(X + (size_t)(a0 + r) * DD + k0);
#pragma unroll
    for (int f = 0; f < 4; ++f) {
      float4 v = s4[f];
      ushort4 h, lo;
      h.x = bfbits(v.x); lo.x = bfbits(v.x - bfval(h.x));
      h.y = bfbits(v.y); lo.y = bfbits(v.y - bfval(h.y));
      h.z = bfbits(v.z); lo.z = bfbits(v.z - bfval(h.z));
      h.w = bfbits(v.w); lo.w = bfbits(v.w - bfval(h.w));
      *(ushort4*)&Xh[r * SH + k0 + f * 4] = h;
      *(ushort4*)&Xl[r * SH + k0 + f * 4] = lo;
    }
  }

  const int l    = t & 63;
  const int w    = t >> 6;
  const int mrow = w * 16 + (l & 15);
  const int kq   = (l >> 4) * 8;
  const int cc   = l & 15;

#pragma unroll
  for (int side = 0; side < 2; ++side) {
    f32x4 acc[4];
#pragma unroll
    for (int j = 0; j < 4; ++j) acc[j] = (f32x4){0.f, 0.f, 0.f, 0.f};
#pragma unroll
    for (int s = 0; s < 2; ++s) {
      bf16x8 ah = ldfrag(&Xh[mrow * SH + s * 32 + kq]);
      bf16x8 al = ldfrag(&Xl[mrow * SH + s * 32 + kq]);
#pragma unroll
      for (int j = 0; j < 4; ++j) {
        const int fo = side * 4096 + ((j * 2 + s) * 64 + l) * 8;
        bf16x8 bh = ldfrag(whi + fo);
        bf16x8 bl = ldfrag(wlo + fo);
        acc[j] = mfma16(al, bh, acc[j]);
        acc[j] = mfma16(ah, bl, acc[j]);
        acc[j] = mfma16(ah, bh, acc[j]);
      }
    }
    float* Y = side ? Ys : Yd;
#pragma unroll
    for (int j = 0; j < 4; ++j) {
      const int   c  = j * 16 + cc;
      const float bb = side ? 0.f : b0[c];
#pragma unroll
      for (int i = 0; i < 4; ++i) {
        const int r = w * 16 + (l >> 4) * 4 + i;
        Y[(size_t)(a0 + r) * DD + c] = acc[j][i] + bb;
      }
    }
  }
}

// ===========================================================================
// edge_kernel_v3: WG = 4 consecutive 64-edge tiles (dst-sorted), software-
// pipelined. Register prefetch of next tile's gather overlaps current tile's
// MFMA. Raw lgkmcnt barriers keep loads in flight.
// LDS hazards per tile: A(msg free) convert->H1, B(H1 ready) L1 MFMA ->H2
// (band-local), C(H1 reads done) L2 MFMA -> msg(aliases H1), D(msg ready)
// reduce. All band-local except reduce + staging.
// ===========================================================================
__global__ __launch_bounds__(256, 4)
void edge_kernel_v3(const float* __restrict__ Yd,
                    const float* __restrict__ Ys,
                    const int* __restrict__ edge_src,
                    const int* __restrict__ edge_dst,
                    const int* __restrict__ eids,
                    const unsigned short* __restrict__ whi,
                    const unsigned short* __restrict__ wlo,
                    const float* __restrict__ b1,
                    const float* __restrict__ b2,
                    float* __restrict__ new_states)
{
  __shared__ __align__(16) unsigned short H1[2 * 64 * SH];  // h1 hi|lo; aliased by msg fp32
  __shared__ __align__(16) unsigned short H2[2 * 64 * SH];  // h2 hi|lo
  __shared__ int dstS[TILES][64];
  __shared__ int srcS[TILES][64];
  __shared__ int segStart[TILES][65];
  __shared__ int segCount[TILES];

  unsigned short* H1h = H1;
  unsigned short* H1l = H1 + 64 * SH;
  unsigned short* H2h = H2;
  unsigned short* H2l = H2 + 64 * SH;
  float* msg = (float*)H1;   // 64*PADE*4 = 17408 B <= 18432 B

  const int t  = threadIdx.x;
  const int e0 = blockIdx.x * (TILES * 64);

  // ---- stage all tiles' indices (coalesced eids read, random dst/src gather)
  {
    const int e = eids[e0 + t];
    dstS[t >> 6][t & 63] = edge_dst[e];
    srcS[t >> 6][t & 63] = edge_src[e];
  }
  __syncthreads();

  // ---- segment detection: wave w handles tile w
  {
    const int lane = t & 63, tile = t >> 6;
    const int d = dstS[tile][lane];
    bool isStart = (lane == 0) || (d != dstS[tile][lane - 1]);
    unsigned long long m = __ballot(isStart);
    if (isStart) {
      unsigned long long below = (lane == 0) ? 0ull : (m & ((1ull << lane) - 1ull));
      segStart[tile][__popcll(below)] = lane;
    }
    if (lane == 0) { int ns = __popcll(m); segCount[tile] = ns; segStart[tile][ns] = 64; }
  }
  // (segStart becomes visible to all waves at the next barrier, before any use)

  const int l    = t & 63;
  const int w    = t >> 6;
  const int mrow = w * 16 + (l & 15);
  const int kq   = (l >> 4) * 8;
  const int cc   = l & 15;
  const int ge   = t >> 2;          // gather: edge within tile
  const int gk0  = (t & 3) * 16;    // gather: feature offset

  float4 pa[4], pb[4];              // prefetch registers (Yd / Ys rows)

  // prefetch tile 0
  {
    const float4* pd = (const float4*)(Yd + (size_t)dstS[0][ge] * DD + gk0);
    const float4* ps = (const float4*)(Ys + (size_t)srcS[0][ge] * DD + gk0);
#pragma unroll
    for (int f = 0; f < 4; ++f) { pa[f] = pd[f]; pb[f] = ps[f]; }
  }

  for (int it = 0; it < TILES; ++it) {
    if (it > 0) bar_lds();   // A: previous tile's msg reads complete

    // ---- convert prefetched gather -> h1 hi/lo (band-local rows)
#pragma unroll
    for (int f = 0; f < 4; ++f) {
      float4 a = pa[f], b = pb[f];
      float4 v = make_float4(relu(a.x + b.x), relu(a.y + b.y),
                             relu(a.z + b.z), relu(a.w + b.w));
      ushort4 h, lo;
      h.x = bfbits(v.x); lo.x = bfbits(v.x - bfval(h.x));
      h.y = bfbits(v.y); lo.y = bfbits(v.y - bfval(h.y));
      h.z = bfbits(v.z); lo.z = bfbits(v.z - bfval(h.z));
      h.w = bfbits(v.w); lo.w = bfbits(v.w - bfval(h.w));
      *(ushort4*)&H1h[ge * SH + gk0 + f * 4] = h;
      *(ushort4*)&H1l[ge * SH + gk0 + f * 4] = lo;
    }

    // ---- issue prefetch for next tile (stays in flight across barriers)
    if (it + 1 < TILES) {
      const float4* pd = (const float4*)(Yd + (size_t)dstS[it + 1][ge] * DD + gk0);
      const float4* ps = (const float4*)(Ys + (size_t)srcS[it + 1][ge] * DD + gk0);
#pragma unroll
      for (int f = 0; f < 4; ++f) { pa[f] = pd[f]; pb[f] = ps[f]; }
    }

    bar_lds();   // B: H1 ready (+ segStart visible for it==0)

    f32x4 acc[4];

    // ---- layer 1 (A = h1, B sec 2) -> h2 hi/lo (band-local)
#pragma unroll
    for (int j = 0; j < 4; ++j) acc[j] = (f32x4){0.f, 0.f, 0.f, 0.f};
#pragma unroll
    for (int s = 0; s < 2; ++s) {
      bf16x8 ah = ldfrag(&H1h[mrow * SH + s * 32 + kq]);
      bf16x8 al = ldfrag(&H1l[mrow * SH + s * 32 + kq]);
#pragma unroll
      for (int j = 0; j < 4; ++j) {
        const int fo = 2 * 4096 + ((j * 2 + s) * 64 + l) * 8;
        bf16x8 bh = ldfrag(whi + fo);
        bf16x8 bl = ldfrag(wlo + fo);
        acc[j] = mfma16(al, bh, acc[j]);
        acc[j] = mfma16(ah, bl, acc[j]);
        acc[j] = mfma16(ah, bh, acc[j]);
      }
    }
#pragma unroll
    for (int j = 0; j < 4; ++j) {
      const int   c  = j * 16 + cc;
      const float bb = b1[c];
#pragma unroll
      for (int i = 0; i < 4; ++i) {
        const int r = w * 16 + (l >> 4) * 4 + i;
        float v = relu(acc[j][i] + bb);
        unsigned short hi = bfbits(v);
        H2h[r * SH + c] = hi;
        H2l[r * SH + c] = bfbits(v - bfval(hi));
      }
    }

    bar_lds();   // C: all waves' H1 reads done (msg may overwrite H1)

    // ---- layer 2 (A = h2, B sec 3) -> msg fp32 (aliases H1)
#pragma unroll
    for (int j = 0; j < 4; ++j) acc[j] = (f32x4){0.f, 0.f, 0.f, 0.f};
#pragma unroll
    for (int s = 0; s < 2; ++s) {
      bf16x8 ah = ldfrag(&H2h[mrow * SH + s * 32 + kq]);
      bf16x8 al = ldfrag(&H2l[mrow * SH + s * 32 + kq]);
#pragma unroll
      for (int j = 0; j < 4; ++j) {
        const int fo = 3 * 4096 + ((j * 2 + s) * 64 + l) * 8;
        bf16x8 bh = ldfrag(whi + fo);
        bf16x8 bl = ldfrag(wlo + fo);
        acc[j] = mfma16(al, bh, acc[j]);
        acc[j] = mfma16(ah, bl, acc[j]);
        acc[j] = mfma16(ah, bh, acc[j]);
      }
    }
#pragma unroll
    for (int j = 0; j < 4; ++j) {
      const int   c  = j * 16 + cc;
      const float bb = b2[c];
#pragma unroll
      for (int i = 0; i < 4; ++i) {
        const int r = w * 16 + (l >> 4) * 4 + i;
        msg[r * PADE + c] = relu(acc[j][i] + bb);
      }
    }

    bar_lds();   // D: msg ready

    // ---- segmented reduction over dst runs of this tile
    {
      const int c = t & 63;
      const int g = t >> 6;
      const int ns = segCount[it];
      for (int s = g; s < ns; s += 4) {
        const int r0 = segStart[it][s], r1 = segStart[it][s + 1];
        float sum = 0.f;
        for (int r = r0; r < r1; ++r) sum += msg[r * PADE + c];
        float* p = new_states + (size_t)dstS[it][r0] * DD + c;
        if (s == 0 || s == ns - 1) atomicAdd(p, sum);
        else *p = sum;
      }
    }
  }
}

// ===========================================================================
// Tier-2 fallback edge kernel (ws too small for Yd/Ys): R4 structure.
// ===========================================================================
__global__ __launch_bounds__(256, 3)
void edge_kernel_t2(const float* __restrict__ atom_states,
                    const int* __restrict__ edge_src,
                    const int* __restrict__ edge_dst,
                    const int* __restrict__ eids,
                    const unsigned short* __restrict__ whi,
                    const unsigned short* __restrict__ wlo,
                    const float* __restrict__ b0,
                    const float* __restrict__ b1,
                    const float* __restrict__ b2,
                    float* __restrict__ new_states)
{
  __shared__ __align__(16) unsigned short Ahi[64 * SA];
  __shared__ __align__(16) unsigned short Alo[64 * SA];
  __shared__ __align__(16) unsigned short Hbuf[2 * 64 * SH];
  __shared__ int eidS[64], dstS[64], segStart[65], segCount;

  unsigned short* Hhi = Hbuf;
  unsigned short* Hlo = Hbuf + 64 * SH;
  float* msg = (float*)Hbuf;

  const int t  = threadIdx.x;
  const int e0 = blockIdx.x * 64;

  if (t < 64) { int e = eids[e0 + t]; eidS[t] = e; dstS[t] = edge_dst[e]; }
  __syncthreads();

  if (t < 64) {
    bool isStart = (t == 0) || (dstS[t] != dstS[t - 1]);
    unsigned long long m = __ballot(isStart);
    if (isStart) {
      unsigned long long below = (t == 0) ? 0ull : (m & ((1ull << t) - 1ull));
      segStart[__popcll(below)] = t;
    }
    if (t == 0) { int ns = __popcll(m); segCount = ns; segStart[ns] = 64; }
  }

  {
    const int job  = t >> 1;
    const int e    = job & 63;
    const int side = job >> 6;
    const int k0   = (t & 1) * 32;
    const int atom = side ? edge_src[eidS[e]] : dstS[e];
    const float4* s4 = (const float4*)(atom_states + (size_t)atom * DD + k0);
    const int rowoff = e * SA + side * 64 + k0;
#pragma unroll
    for (int f = 0; f < 8; ++f) {
      float4 v = s4[f];
      ushort4 h, lo;
      h.x = bfbits(v.x); lo.x = bfbits(v.x - bfval(h.x));
      h.y = bfbits(v.y); lo.y = bfbits(v.y - bfval(h.y));
      h.z = bfbits(v.z); lo.z = bfbits(v.z - bfval(h.z));
      h.w = bfbits(v.w); lo.w = bfbits(v.w - bfval(h.w));
      *(ushort4*)&Ahi[rowoff + f * 4] = h;
      *(ushort4*)&Alo[rowoff + f * 4] = lo;
    }
  }
  __syncthreads();

  const int l    = t & 63;
  const int w    = t >> 6;
  const int mrow = w * 16 + (l & 15);
  const int kq   = (l >> 4) * 8;
  const int cc   = l & 15;

  f32x4 acc[4];

#pragma unroll
  for (int j = 0; j < 4; ++j) acc[j] = (f32x4){0.f, 0.f, 0.f, 0.f};
#pragma unroll
  for (int s = 0; s < 4; ++s) {
    bf16x8 ah = ldfrag(&Ahi[mrow * SA + s * 32 + kq]);
    bf16x8 al = ldfrag(&Alo[mrow * SA + s * 32 + kq]);
#pragma unroll
    for (int j = 0; j < 4; ++j) {
      const int fo = (s < 2 ? 0 : 4096) + ((j * 2 + (s & 1)) * 64 + l) * 8;
      bf16x8 bh = ldfrag(whi + fo);
      bf16x8 bl = ldfrag(wlo + fo);
      acc[j] = mfma16(al, bh, acc[j]);
      acc[j] = mfma16(ah, bl, acc[j]);
      acc[j] = mfma16(ah, bh, acc[j]);
    }
  }
#pragma unroll
  for (int j = 0; j < 4; ++j) {
    const int   c  = j * 16 + cc;
    const float bb = b0[c];
#pragma unroll
    for (int i = 0; i < 4; ++i) {
      const int r = w * 16 + (l >> 4) * 4 + i;
      float v = relu(acc[j][i] + bb);
      unsigned short hi = bfbits(v);
      Hhi[r * SH + c] = hi;
      Hlo[r * SH + c] = bfbits(v - bfval(hi));
    }
  }
  __syncthreads();

#pragma unroll
  for (int j = 0; j < 4; ++j) acc[j] = (f32x4){0.f, 0.f, 0.f, 0.f};
#pragma unroll
  for (int s = 0; s < 2; ++s) {
    bf16x8 ah = ldfrag(&Hhi[mrow * SH + s * 32 + kq]);
    bf16x8 al = ldfrag(&Hlo[mrow * SH + s * 32 + kq]);
#pragma unroll
    for (int j = 0; j < 4; ++j) {
      const int fo = 2 * 4096 + ((j * 2 + s) * 64 + l) * 8;
      bf16x8 bh = ldfrag(whi + fo);
      bf16x8 bl = ldfrag(wlo + fo);
      acc[j] = mfma16(al, bh, acc[j]);
      acc[j] = mfma16(ah, bl, acc[j]);
      acc[j] = mfma16(ah, bh, acc[j]);
    }
  }
#pragma unroll
  for (int j = 0; j < 4; ++j) {
    const int   c  = j * 16 + cc;
    const float bb = b1[c];
#pragma unroll
    for (int i = 0; i < 4; ++i) {
      const int r = w * 16 + (l >> 4) * 4 + i;
      float v = relu(acc[j][i] + bb);
      unsigned short hi = bfbits(v);
      Ahi[r * SA + c] = hi;
      Alo[r * SA + c] = bfbits(v - bfval(hi));
    }
  }
  __syncthreads();

#pragma unroll
  for (int j = 0; j < 4; ++j) acc[j] = (f32x4){0.f, 0.f, 0.f, 0.f};
#pragma unroll
  for (int s = 0; s < 2; ++s) {
    bf16x8 ah = ldfrag(&Ahi[mrow * SA + s * 32 + kq]);
    bf16x8 al = ldfrag(&Alo[mrow * SA + s * 32 + kq]);
#pragma unroll
    for (int j = 0; j < 4; ++j) {
      const int fo = 3 * 4096 + ((j * 2 + s) * 64 + l) * 8;
      bf16x8 bh = ldfrag(whi + fo);
      bf16x8 bl = ldfrag(wlo + fo);
      acc[j] = mfma16(al, bh, acc[j]);
      acc[j] = mfma16(ah, bl, acc[j]);
      acc[j] = mfma16(ah, bh, acc[j]);
    }
  }
#pragma unroll
  for (int j = 0; j < 4; ++j) {
    const int   c  = j * 16 + cc;
    const float bb = b2[c];
#pragma unroll
    for (int i = 0; i < 4; ++i) {
      const int r = w * 16 + (l >> 4) * 4 + i;
      msg[r * PADE + c] = relu(acc[j][i] + bb);
    }
  }
  __syncthreads();

  {
    const int c = t & 63;
    const int g = t >> 6;
    const int ns = segCount;
    for (int s = g; s < ns; s += 4) {
      const int r0 = segStart[s], r1 = segStart[s + 1];
      float sum = 0.f;
      for (int r = r0; r < r1; ++r) sum += msg[r * PADE + c];
      float* p = new_states + (size_t)dstS[r0] * DD + c;
      if (s == 0 || s == ns - 1) atomicAdd(p, sum);
      else *p = sum;
    }
  }
}

// ===========================================================================
// atom_kernel_v2: readout MFMA (fc1 sec 4, fc2 sec 5) + fp32 out + mol sum.
// ===========================================================================
__global__ __launch_bounds__(256, 4)
void atom_kernel_v2(const float* __restrict__ ns,
                    const unsigned short* __restrict__ whi,
                    const unsigned short* __restrict__ wlo,
                    const float* __restrict__ f1b,
                    const float* __restrict__ f2b,
                    const float* __restrict__ wo,
                    const float* __restrict__ bo,
                    float* __restrict__ out)
{
  __shared__ __align__(16) unsigned short Xb[2 * 64 * SH];
  __shared__ __align__(16) unsigned short Hb[2 * 64 * SH];
  unsigned short* Xh = Xb;
  unsigned short* Xl = Xb + 64 * SH;
  unsigned short* Hh = Hb;
  unsigned short* Hl = Hb + 64 * SH;
  float* h2f = (float*)Xb;
  float* oS  = (float*)Hb;

  const int t  = threadIdx.x;
  const int a0 = blockIdx.x * 64;

  {
    const int r  = t >> 2;
    const int k0 = (t & 3) * 16;
    const float4* s4 = (const float4*)(ns + (size_t)(a0 + r) * DD + k0);
#pragma unroll
    for (int f = 0; f < 4; ++f) {
      float4 v = s4[f];
      ushort4 h, lo;
      h.x = bfbits(v.x); lo.x = bfbits(v.x - bfval(h.x));
      h.y = bfbits(v.y); lo.y = bfbits(v.y - bfval(h.y));
      h.z = bfbits(v.z); lo.z = bfbits(v.z - bfval(h.z));
      h.w = bfbits(v.w); lo.w = bfbits(v.w - bfval(h.w));
      *(ushort4*)&Xh[r * SH + k0 + f * 4] = h;
      *(ushort4*)&Xl[r * SH + k0 + f * 4] = lo;
    }
  }

  const int l    = t & 63;
  const int w    = t >> 6;
  const int mrow = w * 16 + (l & 15);
  const int kq   = (l >> 4) * 8;
  const int cc   = l & 15;

  f32x4 acc[4];

#pragma unroll
  for (int j = 0; j < 4; ++j) acc[j] = (f32x4){0.f, 0.f, 0.f, 0.f};
#pragma unroll
  for (int s = 0; s < 2; ++s) {
    bf16x8 ah = ldfrag(&Xh[mrow * SH + s * 32 + kq]);
    bf16x8 al = ldfrag(&Xl[mrow * SH + s * 32 + kq]);
#pragma unroll
    for (int j = 0; j < 4; ++j) {
      const int fo = 4 * 4096 + ((j * 2 + s) * 64 + l) * 8;
      bf16x8 bh = ldfrag(whi + fo);
      bf16x8 bl = ldfrag(wlo + fo);
      acc[j] = mfma16(al, bh, acc[j]);
      acc[j] = mfma16(ah, bl, acc[j]);
      acc[j] = mfma16(ah, bh, acc[j]);
    }
  }
#pragma unroll
  for (int j = 0; j < 4; ++j) {
    const int   c  = j * 16 + cc;
    const float bb = f1b[c];
#pragma unroll
    for (int i = 0; i < 4; ++i) {
      const int r = w * 16 + (l >> 4) * 4 + i;
      float v = relu(acc[j][i] + bb);
      unsigned short hi = bfbits(v);
      Hh[r * SH + c] = hi;
      Hl[r * SH + c] = bfbits(v - bfval(hi));
    }
  }
  __syncthreads();

#pragma unroll
  for (int j = 0; j < 4; ++j) acc[j] = (f32x4){0.f, 0.f, 0.f, 0.f};
#pragma unroll
  for (int s = 0; s < 2; ++s) {
    bf16x8 ah = ldfrag(&Hh[mrow * SH + s * 32 + kq]);
    bf16x8 al = ldfrag(&Hl[mrow * SH + s * 32 + kq]);
#pragma unroll
    for (int j = 0; j < 4; ++j) {
      const int fo = 5 * 4096 + ((j * 2 + s) * 64 + l) * 8;
      bf16x8 bh = ldfrag(whi + fo);
      bf16x8 bl = ldfrag(wlo + fo);
      acc[j] = mfma16(al, bh, acc[j]);
      acc[j] = mfma16(ah, bl, acc[j]);
      acc[j] = mfma16(ah, bh, acc[j]);
    }
  }
#pragma unroll
  for (int j = 0; j < 4; ++j) {
    const int   c  = j * 16 + cc;
    const float bb = f2b[c];
#pragma unroll
    for (int i = 0; i < 4; ++i) {
      const int r = w * 16 + (l >> 4) * 4 + i;
      h2f[r * PADE + c] = relu(acc[j][i] + bb);
    }
  }
  __syncthreads();

  {
    const int r  = t >> 2;
    const int c4 = (t & 3) * 4;
    float o4[4] = {0.f, 0.f, 0.f, 0.f};
#pragma unroll 8
    for (int k = 0; k < 64; ++k) {
      const float a = h2f[r * PADE + k];
      float4 bw = *(const float4*)&wo[k * OUTD + c4];
      o4[0] += a * bw.x; o4[1] += a * bw.y; o4[2] += a * bw.z; o4[3] += a * bw.w;
    }
#pragma unroll
    for (int j = 0; j < 4; ++j)
      oS[r * 17 + c4 + j] = relu(o4[j] + bo[c4 + j]);
  }
  __syncthreads();

  if (t < 32) {
    const int m = t >> 4;
    const int c = t & 15;
    float s = 0.f;
#pragma unroll
    for (int a = 0; a < 32; ++a) s += oS[(m * 32 + a) * 17 + c];
    out[(blockIdx.x * 2 + m) * OUTD + c] = s;
  }
}

// ===========================================================================
extern "C" void kernel_launch(void* const* d_in, const int* in_sizes, int n_in,
                              void* d_out, int out_size, void* d_ws, size_t ws_size,
                              hipStream_t stream) {
  const float* atom_states = (const float*)d_in[0];
  const int*   edge_src    = (const int*)d_in[1];
  const int*   edge_dst    = (const int*)d_in[2];
  const float* ms0_w = (const float*)d_in[4];
  const float* ms0_b = (const float*)d_in[5];
  const float* ms1_w = (const float*)d_in[6];
  const float* ms1_b = (const float*)d_in[7];
  const float* ms2_w = (const float*)d_in[8];
  const float* ms2_b = (const float*)d_in[9];
  const float* fc1_w = (const float*)d_in[10];
  const float* fc1_b = (const float*)d_in[11];
  const float* fc2_w = (const float*)d_in[12];
  const float* fc2_b = (const float*)d_in[13];
  const float* out_w = (const float*)d_in[14];
  const float* out_b = (const float*)d_in[15];

  char* ws = (char*)d_ws;
  float* new_states = (float*)ws;
  size_t off = (size_t)N_ATOMS * DD * sizeof(float);                   // 32 MiB
  int* eids     = (int*)(ws + off); off += (size_t)N_EDGES * 4;        // +4 MiB
  int* counters = (int*)(ws + off); off += (size_t)N_ATOMS * 4;        // +512 KiB
  int* cursor   = (int*)(ws + off); off += (size_t)N_ATOMS * 4;        // +512 KiB
  int* partial  = (int*)(ws + off); off += 4096;                       // +4 KiB
  unsigned short* whi = (unsigned short*)(ws + off); off += 24576 * 2; // +48 KiB
  unsigned short* wlo = (unsigned short*)(ws + off); off += 24576 * 2; // +48 KiB
  float* Yd = (float*)(ws + off); off += (size_t)N_ATOMS * DD * sizeof(float);
  float* Ys = (float*)(ws + off); off += (size_t)N_ATOMS * DD * sizeof(float);
  const size_t need1 = off;   // ~101 MiB

  hipMemsetAsync(new_states, 0, (size_t)N_ATOMS * DD * sizeof(float), stream);
  hipMemsetAsync(counters, 0, (size_t)N_ATOMS * 4, stream);

  weight_prep<<<12, 256, 0, stream>>>(ms0_w, ms1_w, ms2_w, fc1_w, fc2_w, whi, wlo);
  hist_kernel<<<N_EDGES / 256, 256, 0, stream>>>(edge_dst, counters);
  blocksum_kernel<<<512, 256, 0, stream>>>(counters, partial);
  scanwrite_kernel<<<512, 256, 0, stream>>>(counters, partial, cursor);
  scatter_kernel<<<N_EDGES / 256, 256, 0, stream>>>(edge_dst, cursor, eids);

  if (ws_size >= need1) {
    atom_pre<<<N_ATOMS / 64, 256, 0, stream>>>(atom_states, whi, wlo, ms0_b, Yd, Ys);
    edge_kernel_v3<<<N_EDGES / (TILES * 64), 256, 0, stream>>>(
        Yd, Ys, edge_src, edge_dst, eids, whi, wlo, ms1_b, ms2_b, new_states);
  } else {
    edge_kernel_t2<<<N_EDGES / 64, 256, 0, stream>>>(
        atom_states, edge_src, edge_dst, eids, whi, wlo,
        ms0_b, ms1_b, ms2_b, new_states);
  }

  atom_kernel_v2<<<N_ATOMS / 64, 256, 0, stream>>>(
      new_states, whi, wlo, fc1_b, fc2_b, out_w, out_b, (float*)d_out);
}